// Round 1
// baseline (639.671 us; speedup 1.0000x reference)
//
#include <hip/hip_runtime.h>
#include <math.h>

#define NK 512
#define DD 256
#define NB 32
#define NT 4096

#define BT 128      // t per block
#define BK 128      // k per chunk
#define DCHUNK 32   // d per LDS stage
#define NKC (NK / BK)       // 4
#define NDC (DD / DCHUNK)   // 8
#define WSTR (BK + 4)       // 132 floats: keeps 16B row alignment, caps transpose-write conflicts at 4-way

// ---------------------------------------------------------------------------
// wsq[k] = sum_d W[k][d]^2, accumulated in fp64, rounded once to fp32.
// ---------------------------------------------------------------------------
__global__ __launch_bounds__(256) void wsq_kernel(const float* __restrict__ W,
                                                  float* __restrict__ wsq) {
    int k = blockIdx.x * blockDim.x + threadIdx.x;
    if (k >= NK) return;
    const float4* row = (const float4*)(W + (size_t)k * DD);
    double s = 0.0;
    #pragma unroll 8
    for (int i = 0; i < DD / 4; ++i) {
        float4 v = row[i];
        s += (double)v.x * v.x + (double)v.y * v.y + (double)v.z * v.z + (double)v.w * v.w;
    }
    wsq[k] = (float)s;
}

// ---------------------------------------------------------------------------
// Main kernel: per block, 128 t's (one b) vs all 512 codes.
// dist = fl(fl(zsq - fl(2*cross)) + wsq)  -- mimics reference fp32 rounding.
// Ties -> lowest k (numpy argmin semantics), lexicographic everywhere.
// ---------------------------------------------------------------------------
__global__ __launch_bounds__(256) void vq_kernel(const float* __restrict__ Z,
                                                 const float* __restrict__ W,
                                                 const float* __restrict__ wsq_g,
                                                 int* __restrict__ out) {
    __shared__ __align__(16) float Zs[DCHUNK * BT];    // [d][t]   16 KB
    __shared__ __align__(16) float Ws[DCHUNK * WSTR];  // [d][k]   16.5 KB (padded)
    __shared__ float wsqs[NK];                         // 2 KB

    const int tid = threadIdx.x;
    const int tx  = tid & 15;   // k-group: covers k_local = tx*8 .. tx*8+7
    const int ty  = tid >> 4;   // t-group: covers t_local = ty*8 .. ty*8+7
    const int b   = blockIdx.y;
    const int t0  = blockIdx.x * BT;

    // Fill wsqs (from precomputed global, or in-block fallback if no workspace)
    if (wsq_g) {
        wsqs[tid]       = wsq_g[tid];
        wsqs[tid + 256] = wsq_g[tid + 256];
    } else {
        for (int k = tid; k < NK; k += 256) {
            const float4* row = (const float4*)(W + (size_t)k * DD);
            double s = 0.0;
            for (int i = 0; i < DD / 4; ++i) {
                float4 v = row[i];
                s += (double)v.x * v.x + (double)v.y * v.y + (double)v.z * v.z + (double)v.w * v.w;
            }
            wsqs[k] = (float)s;
        }
    }

    const float* Zb = Z + (size_t)b * DD * NT + t0;  // row d lives at Zb + d*NT

    float best[8];
    int   bidx[8];
    #pragma unroll
    for (int a = 0; a < 8; ++a) { best[a] = INFINITY; bidx[a] = 0x7fffffff; }

    double zsqd[8];
    #pragma unroll
    for (int a = 0; a < 8; ++a) zsqd[a] = 0.0;
    float zsqf[8];

    for (int kc = 0; kc < NKC; ++kc) {
        float acc[8][8];
        #pragma unroll
        for (int a = 0; a < 8; ++a)
            #pragma unroll
            for (int c = 0; c < 8; ++c) acc[a][c] = 0.f;

        for (int dc = 0; dc < NDC; ++dc) {
            const int d0 = dc * DCHUNK;
            __syncthreads();  // previous stage's readers done before overwrite

            // ---- stage Z: 32 d-rows x 128 t, coalesced float4, no transpose
            #pragma unroll
            for (int i = 0; i < 4; ++i) {
                int f  = tid + i * 256;   // 0..1023 float4 slots
                int r  = f >> 5;          // d row 0..31
                int c4 = f & 31;          // t quad 0..31
                float4 v = *(const float4*)(Zb + (size_t)(d0 + r) * NT + c4 * 4);
                *(float4*)(&Zs[r * BT + c4 * 4]) = v;
            }
            // ---- stage W transposed: read [k][d] float4 coalesced, scatter to [d][k]
            #pragma unroll
            for (int i = 0; i < 4; ++i) {
                int u  = tid + i * 256;
                int k  = u >> 3;          // 0..127
                int rg = u & 7;           // d quad 0..7
                float4 v = *(const float4*)(W + (size_t)(kc * BK + k) * DD + d0 + rg * 4);
                Ws[(rg * 4 + 0) * WSTR + k] = v.x;
                Ws[(rg * 4 + 1) * WSTR + k] = v.y;
                Ws[(rg * 4 + 2) * WSTR + k] = v.z;
                Ws[(rg * 4 + 3) * WSTR + k] = v.w;
            }
            __syncthreads();

            // ---- 8x8 outer-product microkernel
            #pragma unroll 4
            for (int d = 0; d < DCHUNK; ++d) {
                float4 z0 = *(const float4*)(&Zs[d * BT + ty * 8]);
                float4 z1 = *(const float4*)(&Zs[d * BT + ty * 8 + 4]);
                float4 w0 = *(const float4*)(&Ws[d * WSTR + tx * 8]);
                float4 w1 = *(const float4*)(&Ws[d * WSTR + tx * 8 + 4]);
                float za[8] = {z0.x, z0.y, z0.z, z0.w, z1.x, z1.y, z1.z, z1.w};
                float wa[8] = {w0.x, w0.y, w0.z, w0.w, w1.x, w1.y, w1.z, w1.w};
                if (kc == 0) {  // uniform branch; zsq over full d happens during chunk 0
                    #pragma unroll
                    for (int a = 0; a < 8; ++a)
                        zsqd[a] = fma((double)za[a], (double)za[a], zsqd[a]);
                }
                #pragma unroll
                for (int a = 0; a < 8; ++a)
                    #pragma unroll
                    for (int c = 0; c < 8; ++c)
                        acc[a][c] = fmaf(za[a], wa[c], acc[a][c]);
            }
        }

        if (kc == 0) {
            #pragma unroll
            for (int a = 0; a < 8; ++a) zsqf[a] = (float)zsqd[a];
        }

        // ---- chunk epilogue: reference-faithful rounding chain, running argmin
        #pragma unroll
        for (int c = 0; c < 8; ++c) {
            int   kg = kc * BK + tx * 8 + c;
            float wq = wsqs[kg];
            #pragma unroll
            for (int a = 0; a < 8; ++a) {
                float c2   = __fmul_rn(2.0f, acc[a][c]);   // fl(2*cross)
                float s    = __fsub_rn(zsqf[a], c2);       // fl(zsq - ..)
                float dist = __fadd_rn(s, wq);             // fl(.. + wsq)
                if (dist < best[a] || (dist == best[a] && kg < bidx[a])) {
                    best[a] = dist;
                    bidx[a] = kg;
                }
            }
        }
    }

    // ---- cross-thread (tx) argmin reduction via LDS (reuse Zs/Ws)
    __syncthreads();
    float* redv = Zs;        // need BT*16 = 2048 floats (have 4096)
    int*   redi = (int*)Ws;  // need 2048 ints (have 4224)
    #pragma unroll
    for (int a = 0; a < 8; ++a) {
        int tl = ty * 8 + a;
        redv[tl * 16 + tx] = best[a];
        redi[tl * 16 + tx] = bidx[a];
    }
    __syncthreads();
    if (tid < BT) {
        float bv = INFINITY;
        int   bi = 0x7fffffff;
        #pragma unroll
        for (int j = 0; j < 16; ++j) {
            float v = redv[tid * 16 + j];
            int   i = redi[tid * 16 + j];
            if (v < bv || (v == bv && i < bi)) { bv = v; bi = i; }
        }
        out[(size_t)b * NT + t0 + tid] = bi;
    }
}

extern "C" void kernel_launch(void* const* d_in, const int* in_sizes, int n_in,
                              void* d_out, int out_size, void* d_ws, size_t ws_size,
                              hipStream_t stream) {
    const float* Z = (const float*)d_in[0];   // [B, D, T] fp32
    const float* W = (const float*)d_in[1];   // [K, D] fp32
    int* out = (int*)d_out;                   // [B, T] int32

    float* wsq = nullptr;
    if (ws_size >= NK * sizeof(float)) {
        wsq = (float*)d_ws;
        wsq_kernel<<<dim3(2), dim3(256), 0, stream>>>(W, wsq);
    }

    dim3 grid(NT / BT, NB);  // 32 x 32 = 1024 blocks
    vq_kernel<<<grid, dim3(256), 0, stream>>>(Z, W, wsq, out);
}